// Round 3
// baseline (6952.487 us; speedup 1.0000x reference)
//
#include <hip/hip_runtime.h>
#include <stdint.h>
#include <stddef.h>

#define VOC 32000
#define EMB 512
#define HID 1024
#define BB 64
#define NSTEP 63
#define ROWS 4032
#define ROWSP 4096
#define NTILE 250

typedef unsigned short u16;
typedef unsigned int u32;
typedef unsigned long long u64;
typedef __attribute__((ext_vector_type(8))) short bf16x8;
typedef __attribute__((ext_vector_type(4))) float f32x4;

__device__ __forceinline__ u16 f2bf(float f) {
  u32 u = __float_as_uint(f);
  return (u16)((u + 0x7FFFu + ((u >> 16) & 1u)) >> 16);
}
__device__ __forceinline__ float bf2f(u16 h) { return __uint_as_float(((u32)h) << 16); }

template<int SWAP>
__device__ __forceinline__ f32x4 mfma16(bf16x8 a, bf16x8 b, f32x4 c) {
  if (SWAP) return __builtin_amdgcn_mfma_f32_16x16x32_bf16(b, a, c, 0, 0, 0);
  return __builtin_amdgcn_mfma_f32_16x16x32_bf16(a, b, c, 0, 0, 0);
}

// ---------------- probe: resolve MFMA operand convention at runtime ----------------
__global__ void k_probe(u32* flag) {
  int lane = threadIdx.x & 63;
  int quad = lane >> 4, l15 = lane & 15;
  bf16x8 a, b;
#pragma unroll
  for (int j = 0; j < 8; j++) {
    int k = quad * 8 + j;
    a[j] = (short)f2bf(k == l15 ? 1.0f : 0.0f);
    b[j] = (short)f2bf((float)(l15 + 3));
  }
  f32x4 c = {0.f, 0.f, 0.f, 0.f};
  c = __builtin_amdgcn_mfma_f32_16x16x32_bf16(a, b, c, 0, 0, 0);
  if (threadIdx.x == 1) *flag = (c[0] == 3.0f) ? 1u : 0u;
}

// ---------------- weight prep: W_out -> (hi,lo); W_hh/W_ih -> 3-way bf16 split ----------------
__global__ void __launch_bounds__(256) k_prep_w(
    const float* __restrict__ wout, const float* __restrict__ whh, const float* __restrict__ wih,
    u16* __restrict__ wbh, u16* __restrict__ wbl,
    u16* __restrict__ whhh, u16* __restrict__ whhm, u16* __restrict__ whhl,
    u16* __restrict__ wihh, u16* __restrict__ wihm, u16* __restrict__ wihl) {
  size_t i0 = (size_t)blockIdx.x * blockDim.x + threadIdx.x;
  size_t stride = (size_t)gridDim.x * blockDim.x;
  for (size_t j = i0; j < (size_t)VOC * HID; j += stride) {
    float v = wout[j];
    u16 h = f2bf(v);
    wbh[j] = h; wbl[j] = f2bf(v - bf2f(h));
  }
  for (size_t j = i0; j < (size_t)4096 * HID; j += stride) {
    float v = whh[j];
    u16 h = f2bf(v); float r1 = v - bf2f(h);
    u16 m = f2bf(r1); float r2 = r1 - bf2f(m);
    whhh[j] = h; whhm[j] = m; whhl[j] = f2bf(r2);
  }
  for (size_t j = i0; j < (size_t)4096 * EMB; j += stride) {
    float v = wih[j];
    u16 h = f2bf(v); float r1 = v - bf2f(h);
    u16 m = f2bf(r1); float r2 = r1 - bf2f(m);
    wihh[j] = h; wihm[j] = m; wihl[j] = f2bf(r2);
  }
}

// ---------------- input prep ----------------
__global__ void __launch_bounds__(256) k_prep_x(
    const int* __restrict__ ids, const float* __restrict__ emb,
    const float* __restrict__ h0src, const float* __restrict__ c0src,
    u16* __restrict__ xh, u16* __restrict__ xm, u16* __restrict__ xl,
    u16* __restrict__ h0h, u16* __restrict__ h0m, u16* __restrict__ h0l,
    double* __restrict__ cst, u16* __restrict__ hshi, u16* __restrict__ hslo,
    float* __restrict__ losst) {
  size_t i0 = (size_t)blockIdx.x * blockDim.x + threadIdx.x;
  size_t stride = (size_t)gridDim.x * blockDim.x;
  for (size_t j = i0; j < (size_t)ROWS * EMB; j += stride) {
    size_t r = j >> 9;
    int id = ids[r];
    float v = emb[(size_t)id * EMB + (j & 511)];
    u16 h = f2bf(v); float r1 = v - bf2f(h);
    u16 m = f2bf(r1); float r2 = r1 - bf2f(m);
    xh[j] = h; xm[j] = m; xl[j] = f2bf(r2);
  }
  for (size_t j = i0; j < (size_t)BB * HID; j += stride) {
    float v = h0src[j];
    u16 h = f2bf(v); float r1 = v - bf2f(h);
    u16 m = f2bf(r1); float r2 = r1 - bf2f(m);
    h0h[j] = h; h0m[j] = m; h0l[j] = f2bf(r2);
    cst[j] = (double)c0src[j];
  }
  for (size_t j = i0; j < (size_t)(ROWSP - ROWS) * HID; j += stride) {
    hshi[(size_t)ROWS * HID + j] = 0;
    hslo[(size_t)ROWS * HID + j] = 0;
  }
  if (i0 < 64) losst[i0] = 0.f;
}

// ---------------- LSTM step (round-2 structure, verified 3x) ----------------
template<int SWAP>
__device__ __forceinline__ void step_body(
    const u16* __restrict__ ah, const u16* __restrict__ am, const u16* __restrict__ al,
    const u16* __restrict__ xh, const u16* __restrict__ xm, const u16* __restrict__ xl,
    const u16* __restrict__ whhh, const u16* __restrict__ whhm, const u16* __restrict__ whhl,
    const u16* __restrict__ wihh, const u16* __restrict__ wihm, const u16* __restrict__ wihl,
    const float* __restrict__ bih, const float* __restrict__ bhh,
    double* __restrict__ cst, u16* __restrict__ hshi_t, u16* __restrict__ hslo_t,
    u16* __restrict__ oh, u16* __restrict__ om, u16* __restrict__ ol) {
  __shared__ double lred[8192];
  const int tid = threadIdx.x;
  const int wave = tid >> 6, lane = tid & 63;
  const int quad = lane >> 4, l15 = lane & 15;
  const int mgrp = wave & 3, ks = wave >> 2;
  const int hblk = blockIdx.x;
  const int arow = mgrp * 16 + l15;
  const int wrow = hblk * 16 + l15;
  f32x4 acc[4][4];
#pragma unroll
  for (int g = 0; g < 4; g++)
#pragma unroll
    for (int cg = 0; cg < 4; cg++) acc[g][cg] = (f32x4){0.f, 0.f, 0.f, 0.f};
  {
    const size_t abase = (size_t)arow * HID + ks * 512 + quad * 8;
    for (int c = 0; c < 16; c++) {
      int k = c * 32;
      bf16x8 a0 = *(const bf16x8*)(ah + abase + k);
      bf16x8 a1 = *(const bf16x8*)(am + abase + k);
      bf16x8 a2 = *(const bf16x8*)(al + abase + k);
      int cg = c & 3;
#pragma unroll
      for (int g = 0; g < 4; g++) {
        size_t off = (size_t)(g * HID + wrow) * HID + ks * 512 + quad * 8 + k;
        bf16x8 w0 = *(const bf16x8*)(whhh + off);
        bf16x8 w1 = *(const bf16x8*)(whhm + off);
        bf16x8 w2 = *(const bf16x8*)(whhl + off);
        acc[g][cg] = mfma16<SWAP>(a0, w0, acc[g][cg]);
        acc[g][cg] = mfma16<SWAP>(a1, w0, acc[g][cg]);
        acc[g][cg] = mfma16<SWAP>(a0, w1, acc[g][cg]);
        acc[g][cg] = mfma16<SWAP>(a2, w0, acc[g][cg]);
        acc[g][cg] = mfma16<SWAP>(a1, w1, acc[g][cg]);
        acc[g][cg] = mfma16<SWAP>(a0, w2, acc[g][cg]);
      }
    }
  }
  {
    const size_t xbase = (size_t)arow * EMB + ks * 256 + quad * 8;
    for (int c = 0; c < 8; c++) {
      int k = c * 32;
      bf16x8 a0 = *(const bf16x8*)(xh + xbase + k);
      bf16x8 a1 = *(const bf16x8*)(xm + xbase + k);
      bf16x8 a2 = *(const bf16x8*)(xl + xbase + k);
      int cg = c & 3;
#pragma unroll
      for (int g = 0; g < 4; g++) {
        size_t off = (size_t)(g * HID + wrow) * EMB + ks * 256 + quad * 8 + k;
        bf16x8 w0 = *(const bf16x8*)(wihh + off);
        bf16x8 w1 = *(const bf16x8*)(wihm + off);
        bf16x8 w2 = *(const bf16x8*)(wihl + off);
        acc[g][cg] = mfma16<SWAP>(a0, w0, acc[g][cg]);
        acc[g][cg] = mfma16<SWAP>(a1, w0, acc[g][cg]);
        acc[g][cg] = mfma16<SWAP>(a0, w1, acc[g][cg]);
        acc[g][cg] = mfma16<SWAP>(a2, w0, acc[g][cg]);
        acc[g][cg] = mfma16<SWAP>(a1, w1, acc[g][cg]);
        acc[g][cg] = mfma16<SWAP>(a0, w2, acc[g][cg]);
      }
    }
  }
#pragma unroll
  for (int g = 0; g < 4; g++)
#pragma unroll
    for (int r = 0; r < 4; r++) {
      double d = (double)acc[g][0][r] + (double)acc[g][1][r] +
                 (double)acc[g][2][r] + (double)acc[g][3][r];
      lred[(size_t)((g * 4 + mgrp) * 2 + ks) * 256 + (quad * 4 + r) * 16 + l15] = d;
    }
  __syncthreads();
  for (int u = tid; u < 1024; u += 512) {
    int b = u >> 4, cl = u & 15;
    int mg = b >> 4, rl = (b & 15) * 16 + cl;
    int gcol = hblk * 16 + cl;
    double gv[4];
#pragma unroll
    for (int g = 0; g < 4; g++)
      gv[g] = lred[(size_t)((g * 4 + mg) * 2 + 0) * 256 + rl] +
              lred[(size_t)((g * 4 + mg) * 2 + 1) * 256 + rl] +
              (double)bih[g * HID + gcol] + (double)bhh[g * HID + gcol];
    float i_ = 1.f / (1.f + expf(-(float)gv[0]));
    float f_ = 1.f / (1.f + expf(-(float)gv[1]));
    float g_ = tanhf((float)gv[2]);
    float o_ = 1.f / (1.f + expf(-(float)gv[3]));
    size_t ci = (size_t)b * HID + gcol;
    double cn = (double)f_ * cst[ci] + (double)i_ * (double)g_;
    cst[ci] = cn;
    float hn = o_ * tanhf((float)cn);
    u16 h0 = f2bf(hn); float r1 = hn - bf2f(h0);
    u16 h1 = f2bf(r1); float r2 = r1 - bf2f(h1);
    oh[ci] = h0; om[ci] = h1; ol[ci] = f2bf(r2);
    hshi_t[ci] = h0; hslo_t[ci] = h1;
  }
}

__global__ void __launch_bounds__(512) k_step(
    const u32* __restrict__ flag,
    const u16* ah, const u16* am, const u16* al,
    const u16* xh, const u16* xm, const u16* xl,
    const u16* whhh, const u16* whhm, const u16* whhl,
    const u16* wihh, const u16* wihm, const u16* wihl,
    const float* bih, const float* bhh,
    double* cst, u16* hshi_t, u16* hslo_t, u16* oh, u16* om, u16* ol) {
  if (*flag) step_body<1>(ah, am, al, xh, xm, xl, whhh, whhm, whhl, wihh, wihm, wihl,
                          bih, bhh, cst, hshi_t, hslo_t, oh, om, ol);
  else       step_body<0>(ah, am, al, xh, xm, xl, whhh, whhm, whhl, wihh, wihm, wihl,
                          bih, bhh, cst, hshi_t, hslo_t, oh, om, ol);
}

// ---------------- logits GEMM, 3-product bf16x2 split, fused max/argmax/sumexp/label ----------------
// Per (row, ntile) record (3 u32): [tile max (f32), tile argmax col (u32), tile sumexp (f32)].
// Also vlab[row] = logit at label column (written by the one tile containing it).
template<int SWAP>
__device__ __forceinline__ void logits_body(
    const u16* __restrict__ hsh, const u16* __restrict__ hsl,
    const u16* __restrict__ wbh, const u16* __restrict__ wbl,
    const float* __restrict__ bout, const int* __restrict__ ids,
    u32* __restrict__ part, float* __restrict__ vlab) {
  __shared__ u16 lAh[128 * 32];
  __shared__ u16 lAl[128 * 32];
  __shared__ u16 lBh[128 * 32];
  __shared__ u16 lBl[128 * 32];
  const int tid = threadIdx.x;
  const int wave = tid >> 6, lane = tid & 63;
  const int quad = lane >> 4, l15 = lane & 15;
  const int wm = wave >> 1, wn = wave & 1;
  const int mtile = blockIdx.x, ntile = blockIdx.y;
  const size_t mbase = (size_t)mtile * 128, nbase = (size_t)ntile * 128;
  const int s0 = tid, s1 = tid + 256;
  const int r0 = s0 >> 2, c0 = (s0 & 3) * 8, r1 = s1 >> 2, c1 = (s1 & 3) * 8;
  const u16* gAh0 = hsh + (mbase + r0) * HID + c0;
  const u16* gAh1 = hsh + (mbase + r1) * HID + c1;
  const u16* gAl0 = hsl + (mbase + r0) * HID + c0;
  const u16* gAl1 = hsl + (mbase + r1) * HID + c1;
  const u16* gBh0 = wbh + (nbase + r0) * HID + c0;
  const u16* gBh1 = wbh + (nbase + r1) * HID + c1;
  const u16* gBl0 = wbl + (nbase + r0) * HID + c0;
  const u16* gBl1 = wbl + (nbase + r1) * HID + c1;
  f32x4 acc[4][4];
#pragma unroll
  for (int a = 0; a < 4; a++)
#pragma unroll
    for (int b = 0; b < 4; b++) acc[a][b] = (f32x4){0.f, 0.f, 0.f, 0.f};
  bf16x8 pAh0 = *(const bf16x8*)gAh0, pAh1 = *(const bf16x8*)gAh1;
  bf16x8 pAl0 = *(const bf16x8*)gAl0, pAl1 = *(const bf16x8*)gAl1;
  bf16x8 pBh0 = *(const bf16x8*)gBh0, pBh1 = *(const bf16x8*)gBh1;
  bf16x8 pBl0 = *(const bf16x8*)gBl0, pBl1 = *(const bf16x8*)gBl1;
  for (int k0 = 0; k0 < HID; k0 += 32) {
    __syncthreads();
    *(bf16x8*)&lAh[s0 * 8] = pAh0; *(bf16x8*)&lAh[s1 * 8] = pAh1;
    *(bf16x8*)&lAl[s0 * 8] = pAl0; *(bf16x8*)&lAl[s1 * 8] = pAl1;
    *(bf16x8*)&lBh[s0 * 8] = pBh0; *(bf16x8*)&lBh[s1 * 8] = pBh1;
    *(bf16x8*)&lBl[s0 * 8] = pBl0; *(bf16x8*)&lBl[s1 * 8] = pBl1;
    __syncthreads();
    if (k0 + 32 < HID) {
      int kn = k0 + 32;
      pAh0 = *(const bf16x8*)(gAh0 + kn); pAh1 = *(const bf16x8*)(gAh1 + kn);
      pAl0 = *(const bf16x8*)(gAl0 + kn); pAl1 = *(const bf16x8*)(gAl1 + kn);
      pBh0 = *(const bf16x8*)(gBh0 + kn); pBh1 = *(const bf16x8*)(gBh1 + kn);
      pBl0 = *(const bf16x8*)(gBl0 + kn); pBl1 = *(const bf16x8*)(gBl1 + kn);
    }
    bf16x8 afh[4], afl[4];
#pragma unroll
    for (int mt = 0; mt < 4; mt++) {
      int ab = (wm * 64 + mt * 16 + l15) * 32 + quad * 8;
      afh[mt] = *(const bf16x8*)&lAh[ab];
      afl[mt] = *(const bf16x8*)&lAl[ab];
    }
#pragma unroll
    for (int nt = 0; nt < 4; nt++) {
      int nb = (wn * 64 + nt * 16 + l15) * 32 + quad * 8;
      bf16x8 bh = *(const bf16x8*)&lBh[nb];
      bf16x8 bl = *(const bf16x8*)&lBl[nb];
#pragma unroll
      for (int mt = 0; mt < 4; mt++) {
        acc[mt][nt] = mfma16<SWAP>(afh[mt], bh, acc[mt][nt]);
        acc[mt][nt] = mfma16<SWAP>(afl[mt], bh, acc[mt][nt]);
        acc[mt][nt] = mfma16<SWAP>(afh[mt], bl, acc[mt][nt]);
      }
    }
  }
  __syncthreads();
  // ---- epilogue ----
  float bo[4];
#pragma unroll
  for (int nt = 0; nt < 4; nt++) bo[nt] = bout[nbase + wn * 64 + nt * 16 + l15];
#pragma unroll
  for (int mt = 0; mt < 4; mt++)
#pragma unroll
    for (int nt = 0; nt < 4; nt++)
#pragma unroll
      for (int r = 0; r < 4; r++) acc[mt][nt][r] += bo[nt];
  float* sv = (float*)lAh;   // [wave][64] per-half row max
  int*   sc = (int*)lAl;     // [wave][64] per-half row argmax col
  float* ss = (float*)lBh;   // [wave][64] per-half row sumexp
  // phase 1: per-half (64-col) max + argmax, lowest-index tie-break
  float tval[4][4]; int tcol[4][4]; float se[4][4];
#pragma unroll
  for (int mt = 0; mt < 4; mt++)
#pragma unroll
    for (int r = 0; r < 4; r++) {
      float bv = acc[mt][0][r];
      int bc = (int)nbase + wn * 64 + l15;
#pragma unroll
      for (int nt = 1; nt < 4; nt++) {
        float v = acc[mt][nt][r];
        int c = (int)nbase + wn * 64 + nt * 16 + l15;
        if (v > bv || (v == bv && c < bc)) { bv = v; bc = c; }
      }
#pragma unroll
      for (int d = 1; d < 16; d <<= 1) {
        float ov = __shfl_xor(bv, d);
        int oc = __shfl_xor(bc, d);
        if (ov > bv || (ov == bv && oc < bc)) { bv = ov; bc = oc; }
      }
      if (l15 == 0) {
        sv[wave * 64 + mt * 16 + quad * 4 + r] = bv;
        sc[wave * 64 + mt * 16 + quad * 4 + r] = bc;
      }
    }
  __syncthreads();
  // phase 2: full-tile (128-col) max/argmax
#pragma unroll
  for (int mt = 0; mt < 4; mt++)
#pragma unroll
    for (int r = 0; r < 4; r++) {
      int rl = mt * 16 + quad * 4 + r;
      float mv = sv[wave * 64 + rl]; int mc = sc[wave * 64 + rl];
      float ov = sv[(wave ^ 1) * 64 + rl]; int oc = sc[(wave ^ 1) * 64 + rl];
      if (ov > mv || (ov == mv && oc < mc)) { mv = ov; mc = oc; }
      tval[mt][r] = mv; tcol[mt][r] = mc;
    }
  // phase 3: sumexp per half + label-column extraction
#pragma unroll
  for (int mt = 0; mt < 4; mt++)
#pragma unroll
    for (int r = 0; r < 4; r++) {
      float tm = tval[mt][r];
      float s = 0.f;
#pragma unroll
      for (int nt = 0; nt < 4; nt++) s += __expf(acc[mt][nt][r] - tm);
#pragma unroll
      for (int d = 1; d < 16; d <<= 1) s += __shfl_xor(s, d);
      se[mt][r] = s;
      int row_g = (int)mbase + wm * 64 + mt * 16 + quad * 4 + r;
      if (row_g < ROWS) {
        int lab = ids[row_g + 64];
        int cb = lab - (int)nbase - wn * 64;
        if (cb >= 0 && cb < 64 && (cb & 15) == l15) {
          int ntl = cb >> 4;
          float v = acc[mt][0][r];
#pragma unroll
          for (int nt = 1; nt < 4; nt++) if (ntl == nt) v = acc[mt][nt][r];
          vlab[row_g] = v;
        }
      }
    }
#pragma unroll
  for (int mt = 0; mt < 4; mt++)
#pragma unroll
    for (int r = 0; r < 4; r++)
      if (l15 == 0) ss[wave * 64 + mt * 16 + quad * 4 + r] = se[mt][r];
  __syncthreads();
  // phase 4: write per-(row,tile) record
#pragma unroll
  for (int mt = 0; mt < 4; mt++)
#pragma unroll
    for (int r = 0; r < 4; r++) {
      int rl = mt * 16 + quad * 4 + r;
      int row_g = (int)mbase + wm * 64 + rl;
      if (row_g < ROWS && l15 == 0 && wn == 0) {
        u32* p = part + ((size_t)row_g * NTILE + ntile) * 3;
        p[0] = __float_as_uint(tval[mt][r]);
        p[1] = (u32)tcol[mt][r];
        p[2] = __float_as_uint(se[mt][r] + ss[(wave ^ 1) * 64 + rl]);
      }
    }
}

__global__ void __launch_bounds__(256) k_logits(
    const u32* __restrict__ flag,
    const u16* hsh, const u16* hsl, const u16* wbh, const u16* wbl,
    const float* bout, const int* ids, u32* part, float* vlab) {
  if (*flag) logits_body<1>(hsh, hsl, wbh, wbl, bout, ids, part, vlab);
  else       logits_body<0>(hsh, hsl, wbh, wbl, bout, ids, part, vlab);
}

// ---------------- per-row merge: global argmax (lowest-index ties) + logsumexp + loss ----------------
__global__ void __launch_bounds__(64) k_rowred(
    const u32* __restrict__ part, const float* __restrict__ vlab,
    const int* __restrict__ ids, float* __restrict__ losst, float* __restrict__ dout) {
  int r = blockIdx.x, lane = threadIdx.x;
  float m = -3e38f, s = 0.f;
  int c = 0x7FFFFFFF;
  for (int i = lane; i < NTILE; i += 64) {
    const u32* p = part + ((size_t)r * NTILE + i) * 3;
    float tv = __uint_as_float(p[0]);
    int tc = (int)p[1];
    float ts = __uint_as_float(p[2]);
    if (tv > m || (tv == m && tc < c)) c = tc;
    float nm = fmaxf(m, tv);
    s = s * __expf(m - nm) + ts * __expf(tv - nm);
    m = nm;
  }
#pragma unroll
  for (int d = 1; d < 64; d <<= 1) {
    float om = __shfl_xor(m, d);
    int oc = __shfl_xor(c, d);
    float os = __shfl_xor(s, d);
    if (om > m || (om == m && oc < c)) c = oc;
    float nm = fmaxf(m, om);
    s = s * __expf(m - nm) + os * __expf(om - nm);
    m = nm;
  }
  if (lane == 0) {
    dout[1 + 64 + r] = (float)c;
    int lab = ids[r + 64];
    if (lab != 0) atomicAdd(&losst[r >> 6], (m + __logf(s)) - vlab[r]);
  }
}

// ---------------- finalize ----------------
__global__ void __launch_bounds__(64) k_final(
    const float* __restrict__ losst, const int* __restrict__ ids, float* __restrict__ dout) {
  int lane = threadIdx.x;
  dout[1 + lane] = 1.0f;
  float v = 0.f;
  if (lane < NSTEP) {
    int cnz = 0;
    for (int b2 = 0; b2 < BB; b2++) cnz += (ids[(lane + 1) * BB + b2] != 0);
    v = losst[lane] / (float)max(cnz, 1);
  }
#pragma unroll
  for (int d = 32; d > 0; d >>= 1) v += __shfl_down(v, d);
  if (lane == 0) dout[0] = v;
}

// ---------------- host ----------------
extern "C" void kernel_launch(void* const* d_in, const int* in_sizes, int n_in,
                              void* d_out, int out_size, void* d_ws, size_t ws_size,
                              hipStream_t stream) {
  (void)in_sizes; (void)n_in; (void)out_size; (void)ws_size;
  const int* ids = (const int*)d_in[0];
  const float* hid0 = (const float*)d_in[3];
  const float* cel0 = (const float*)d_in[4];
  const float* emb = (const float*)d_in[5];
  const float* wih = (const float*)d_in[6];
  const float* whh = (const float*)d_in[7];
  const float* bih = (const float*)d_in[8];
  const float* bhh = (const float*)d_in[9];
  const float* wout = (const float*)d_in[10];
  const float* bout = (const float*)d_in[11];
  float* out = (float*)d_out;

  char* ws = (char*)d_ws;
  u16* wbh     = (u16*)(ws + 0ull);            //  65,536,000
  u16* wbl     = (u16*)(ws + 65536000ull);     //  65,536,000
  u16* whh_h   = (u16*)(ws + 131072000ull);    //   8,388,608
  u16* whh_m   = (u16*)(ws + 139460608ull);
  u16* whh_l   = (u16*)(ws + 147849216ull);
  u16* wih_h   = (u16*)(ws + 156237824ull);    //   4,194,304
  u16* wih_m   = (u16*)(ws + 160432128ull);
  u16* wih_l   = (u16*)(ws + 164626432ull);
  u16* xs_h    = (u16*)(ws + 168820736ull);    //   4,128,768
  u16* xs_m    = (u16*)(ws + 172949504ull);
  u16* xs_l    = (u16*)(ws + 177078272ull);
  u16* hs_hi   = (u16*)(ws + 181207040ull);    //   8,388,608 (4096 rows padded)
  u16* hs_lo   = (u16*)(ws + 189595648ull);    //   8,388,608
  u16* pp      = (u16*)(ws + 197984256ull);    //     786,432
  double* cst  = (double*)(ws + 198770688ull); //     524,288
  u32* part    = (u32*)(ws + 199294976ull);    //  12,096,000
  float* vlab  = (float*)(ws + 211390976ull);  //      16,128
  float* losst = (float*)(ws + 211407104ull);  //         256
  u32* flag    = (u32*)(ws + 211407360ull);    //           4

  const size_t HB = (size_t)BB * HID;
  u16* pp0h = pp;            u16* pp0m = pp + HB;     u16* pp0l = pp + 2 * HB;
  u16* pp1h = pp + 3 * HB;   u16* pp1m = pp + 4 * HB; u16* pp1l = pp + 5 * HB;

  k_probe<<<1, 64, 0, stream>>>(flag);
  k_prep_w<<<4096, 256, 0, stream>>>(wout, whh, wih, wbh, wbl,
                                     whh_h, whh_m, whh_l, wih_h, wih_m, wih_l);
  k_prep_x<<<2048, 256, 0, stream>>>(ids, emb, hid0, cel0, xs_h, xs_m, xs_l,
                                     pp0h, pp0m, pp0l, cst, hs_hi, hs_lo, losst);
  for (int t = 0; t < NSTEP; t++) {
    const u16* iah = (t & 1) ? pp1h : pp0h;
    const u16* iam = (t & 1) ? pp1m : pp0m;
    const u16* ial = (t & 1) ? pp1l : pp0l;
    u16* oah = (t & 1) ? pp0h : pp1h;
    u16* oam = (t & 1) ? pp0m : pp1m;
    u16* oal = (t & 1) ? pp0l : pp1l;
    k_step<<<64, 512, 0, stream>>>(flag, iah, iam, ial,
        xs_h + (size_t)t * BB * EMB, xs_m + (size_t)t * BB * EMB, xs_l + (size_t)t * BB * EMB,
        whh_h, whh_m, whh_l, wih_h, wih_m, wih_l, bih, bhh, cst,
        hs_hi + (size_t)t * HB, hs_lo + (size_t)t * HB, oah, oam, oal);
  }
  k_logits<<<dim3(32, 250), 256, 0, stream>>>(flag, hs_hi, hs_lo, wbh, wbl, bout, ids, part, vlab);
  k_rowred<<<ROWS, 64, 0, stream>>>(part, vlab, ids, losst, out);
  k_final<<<1, 64, 0, stream>>>(losst, ids, out);
}

// Round 4
// 4923.841 us; speedup vs baseline: 1.4120x; 1.4120x over previous
//
#include <hip/hip_runtime.h>
#include <stdint.h>
#include <stddef.h>

#define VOC 32000
#define EMB 512
#define HID 1024
#define BB 64
#define NSTEP 63
#define ROWS 4032
#define ROWSP 4096
#define NTILE 250
#define LDA 40   // padded LDS row stride (elements): 80B, 16B-aligned, 2-way banks

typedef unsigned short u16;
typedef unsigned int u32;
typedef unsigned long long u64;
typedef __attribute__((ext_vector_type(8))) short bf16x8;
typedef __attribute__((ext_vector_type(4))) float f32x4;

__device__ __forceinline__ u16 f2bf(float f) {
  u32 u = __float_as_uint(f);
  return (u16)((u + 0x7FFFu + ((u >> 16) & 1u)) >> 16);
}
__device__ __forceinline__ float bf2f(u16 h) { return __uint_as_float(((u32)h) << 16); }

template<int SWAP>
__device__ __forceinline__ f32x4 mfma16(bf16x8 a, bf16x8 b, f32x4 c) {
  if (SWAP) return __builtin_amdgcn_mfma_f32_16x16x32_bf16(b, a, c, 0, 0, 0);
  return __builtin_amdgcn_mfma_f32_16x16x32_bf16(a, b, c, 0, 0, 0);
}

// ---------------- probe: resolve MFMA operand convention at runtime ----------------
__global__ void k_probe(u32* flag) {
  int lane = threadIdx.x & 63;
  int quad = lane >> 4, l15 = lane & 15;
  bf16x8 a, b;
#pragma unroll
  for (int j = 0; j < 8; j++) {
    int k = quad * 8 + j;
    a[j] = (short)f2bf(k == l15 ? 1.0f : 0.0f);
    b[j] = (short)f2bf((float)(l15 + 3));
  }
  f32x4 c = {0.f, 0.f, 0.f, 0.f};
  c = __builtin_amdgcn_mfma_f32_16x16x32_bf16(a, b, c, 0, 0, 0);
  if (threadIdx.x == 1) *flag = (c[0] == 3.0f) ? 1u : 0u;
}

// ---------------- weight prep ----------------
// W_out -> (hi,lo) row-major (k_logits loads are already coalesced).
// W_hh/W_ih -> 3-way bf16 split in MFMA-fragment order so k_step loads are
// lane-contiguous: whh idx group G = ((((hblk*4+g)*2+ks)*16+c)*4+quad)*16+l15,
// element = G*8+j  <->  (row = g*1024+hblk*16+l15, k = ks*512+c*32+quad*8+j).
__global__ void __launch_bounds__(256) k_prep_w(
    const float* __restrict__ wout, const float* __restrict__ whh, const float* __restrict__ wih,
    u16* __restrict__ wbh, u16* __restrict__ wbl,
    u16* __restrict__ whhh, u16* __restrict__ whhm, u16* __restrict__ whhl,
    u16* __restrict__ wihh, u16* __restrict__ wihm, u16* __restrict__ wihl) {
  size_t i0 = (size_t)blockIdx.x * blockDim.x + threadIdx.x;
  size_t stride = (size_t)gridDim.x * blockDim.x;
  for (size_t j = i0; j < (size_t)VOC * HID; j += stride) {
    float v = wout[j];
    u16 h = f2bf(v);
    wbh[j] = h; wbl[j] = f2bf(v - bf2f(h));
  }
  for (size_t G = i0; G < 524288; G += stride) {   // 4096*1024/8
    int l15 = (int)(G & 15), quad = (int)((G >> 4) & 3), c = (int)((G >> 6) & 15);
    int ks = (int)((G >> 10) & 1), g = (int)((G >> 11) & 3), hblk = (int)(G >> 13);
    size_t src = (size_t)(g * 1024 + hblk * 16 + l15) * HID + ks * 512 + c * 32 + quad * 8;
    bf16x8 vh, vm, vl;
#pragma unroll
    for (int j = 0; j < 8; j++) {
      float v = whh[src + j];
      u16 h = f2bf(v); float r1 = v - bf2f(h);
      u16 m = f2bf(r1); float r2 = r1 - bf2f(m);
      vh[j] = (short)h; vm[j] = (short)m; vl[j] = (short)f2bf(r2);
    }
    *(bf16x8*)(whhh + G * 8) = vh;
    *(bf16x8*)(whhm + G * 8) = vm;
    *(bf16x8*)(whhl + G * 8) = vl;
  }
  for (size_t G = i0; G < 262144; G += stride) {   // 4096*512/8
    int l15 = (int)(G & 15), quad = (int)((G >> 4) & 3), c = (int)((G >> 6) & 7);
    int ks = (int)((G >> 9) & 1), g = (int)((G >> 10) & 3), hblk = (int)(G >> 12);
    size_t src = (size_t)(g * 1024 + hblk * 16 + l15) * EMB + ks * 256 + c * 32 + quad * 8;
    bf16x8 vh, vm, vl;
#pragma unroll
    for (int j = 0; j < 8; j++) {
      float v = wih[src + j];
      u16 h = f2bf(v); float r1 = v - bf2f(h);
      u16 m = f2bf(r1); float r2 = r1 - bf2f(m);
      vh[j] = (short)h; vm[j] = (short)m; vl[j] = (short)f2bf(r2);
    }
    *(bf16x8*)(wihh + G * 8) = vh;
    *(bf16x8*)(wihm + G * 8) = vm;
    *(bf16x8*)(wihl + G * 8) = vl;
  }
}

// ---------------- input prep: x/h0 in fragment order, cst(double), pad, zero ----------------
// x idx per step: G = (((ks*8+c)*4+mgrp)*4+quad)*16+l15 <-> (b=mgrp*16+l15, k=ks*256+c*32+quad*8).
// h idx: G = (((ks*16+c)*4+mgrp)*4+quad)*16+l15 <-> (b, k=ks*512+c*32+quad*8).
__global__ void __launch_bounds__(256) k_prep_x(
    const int* __restrict__ ids, const float* __restrict__ emb,
    const float* __restrict__ h0src, const float* __restrict__ c0src,
    u16* __restrict__ xh, u16* __restrict__ xm, u16* __restrict__ xl,
    u16* __restrict__ h0h, u16* __restrict__ h0m, u16* __restrict__ h0l,
    double* __restrict__ cst, u16* __restrict__ hshi, u16* __restrict__ hslo,
    float* __restrict__ losst) {
  size_t i0 = (size_t)blockIdx.x * blockDim.x + threadIdx.x;
  size_t stride = (size_t)gridDim.x * blockDim.x;
  for (size_t G = i0; G < 258048; G += stride) {   // 4032*512/8 groups
    int t = (int)(G >> 12);
    int Gs = (int)(G & 4095);
    int l15 = Gs & 15, quad = (Gs >> 4) & 3, mgrp = (Gs >> 6) & 3;
    int c = (Gs >> 8) & 7, ks = Gs >> 11;
    int b = mgrp * 16 + l15;
    int k = ks * 256 + c * 32 + quad * 8;
    int id = ids[t * 64 + b];
    bf16x8 vh, vm, vl;
#pragma unroll
    for (int j = 0; j < 8; j++) {
      float v = emb[(size_t)id * EMB + k + j];
      u16 h = f2bf(v); float r1 = v - bf2f(h);
      u16 m = f2bf(r1); float r2 = r1 - bf2f(m);
      vh[j] = (short)h; vm[j] = (short)m; vl[j] = (short)f2bf(r2);
    }
    *(bf16x8*)(xh + G * 8) = vh;
    *(bf16x8*)(xm + G * 8) = vm;
    *(bf16x8*)(xl + G * 8) = vl;
  }
  for (size_t G = i0; G < 8192; G += stride) {     // 64*1024/8 groups
    int l15 = (int)(G & 15), quad = (int)((G >> 4) & 3), mgrp = (int)((G >> 6) & 3);
    int c = (int)((G >> 8) & 15), ks = (int)(G >> 12);
    int b = mgrp * 16 + l15;
    int k = ks * 512 + c * 32 + quad * 8;
    bf16x8 vh, vm, vl;
#pragma unroll
    for (int j = 0; j < 8; j++) {
      float v = h0src[(size_t)b * HID + k + j];
      u16 h = f2bf(v); float r1 = v - bf2f(h);
      u16 m = f2bf(r1); float r2 = r1 - bf2f(m);
      vh[j] = (short)h; vm[j] = (short)m; vl[j] = (short)f2bf(r2);
    }
    *(bf16x8*)(h0h + G * 8) = vh;
    *(bf16x8*)(h0m + G * 8) = vm;
    *(bf16x8*)(h0l + G * 8) = vl;
  }
  for (size_t j = i0; j < (size_t)BB * HID; j += stride) cst[j] = (double)c0src[j];
  for (size_t j = i0; j < (size_t)(ROWSP - ROWS) * HID; j += stride) {
    hshi[(size_t)ROWS * HID + j] = 0;
    hslo[(size_t)ROWS * HID + j] = 0;
  }
  if (i0 < 64) losst[i0] = 0.f;
}

// ---------------- LSTM step: all operands in fragment order (coalesced loads) ----------------
template<int SWAP>
__device__ __forceinline__ void step_body(
    const u16* __restrict__ ah, const u16* __restrict__ am, const u16* __restrict__ al,
    const u16* __restrict__ xh, const u16* __restrict__ xm, const u16* __restrict__ xl,
    const u16* __restrict__ whhh, const u16* __restrict__ whhm, const u16* __restrict__ whhl,
    const u16* __restrict__ wihh, const u16* __restrict__ wihm, const u16* __restrict__ wihl,
    const float* __restrict__ bih, const float* __restrict__ bhh,
    double* __restrict__ cst, u16* __restrict__ hshi_t, u16* __restrict__ hslo_t,
    u16* __restrict__ oh, u16* __restrict__ om, u16* __restrict__ ol) {
  __shared__ double lred[8192];
  const int tid = threadIdx.x;
  const int wave = tid >> 6, lane = tid & 63;
  const int quad = lane >> 4, l15 = lane & 15;
  const int mgrp = wave & 3, ks = wave >> 2;
  const int hblk = blockIdx.x;
  const int lane8 = lane * 8;
  f32x4 acc[4][4];
#pragma unroll
  for (int g = 0; g < 4; g++)
#pragma unroll
    for (int cg = 0; cg < 4; cg++) acc[g][cg] = (f32x4){0.f, 0.f, 0.f, 0.f};
  for (int c = 0; c < 16; c++) {
    size_t aoff = (size_t)((ks * 16 + c) * 4 + mgrp) * 512 + lane8;
    bf16x8 a0 = *(const bf16x8*)(ah + aoff);
    bf16x8 a1 = *(const bf16x8*)(am + aoff);
    bf16x8 a2 = *(const bf16x8*)(al + aoff);
    int cg = c & 3;
#pragma unroll
    for (int g = 0; g < 4; g++) {
      size_t woff = (size_t)((((hblk * 4 + g) * 2 + ks) * 16 + c)) * 512 + lane8;
      bf16x8 w0 = *(const bf16x8*)(whhh + woff);
      bf16x8 w1 = *(const bf16x8*)(whhm + woff);
      bf16x8 w2 = *(const bf16x8*)(whhl + woff);
      acc[g][cg] = mfma16<SWAP>(a0, w0, acc[g][cg]);
      acc[g][cg] = mfma16<SWAP>(a1, w0, acc[g][cg]);
      acc[g][cg] = mfma16<SWAP>(a0, w1, acc[g][cg]);
      acc[g][cg] = mfma16<SWAP>(a2, w0, acc[g][cg]);
      acc[g][cg] = mfma16<SWAP>(a1, w1, acc[g][cg]);
      acc[g][cg] = mfma16<SWAP>(a0, w2, acc[g][cg]);
    }
  }
  for (int c = 0; c < 8; c++) {
    size_t xoff = (size_t)((ks * 8 + c) * 4 + mgrp) * 512 + lane8;
    bf16x8 a0 = *(const bf16x8*)(xh + xoff);
    bf16x8 a1 = *(const bf16x8*)(xm + xoff);
    bf16x8 a2 = *(const bf16x8*)(xl + xoff);
    int cg = c & 3;
#pragma unroll
    for (int g = 0; g < 4; g++) {
      size_t woff = (size_t)((((hblk * 4 + g) * 2 + ks) * 8 + c)) * 512 + lane8;
      bf16x8 w0 = *(const bf16x8*)(wihh + woff);
      bf16x8 w1 = *(const bf16x8*)(wihm + woff);
      bf16x8 w2 = *(const bf16x8*)(wihl + woff);
      acc[g][cg] = mfma16<SWAP>(a0, w0, acc[g][cg]);
      acc[g][cg] = mfma16<SWAP>(a1, w0, acc[g][cg]);
      acc[g][cg] = mfma16<SWAP>(a0, w1, acc[g][cg]);
      acc[g][cg] = mfma16<SWAP>(a2, w0, acc[g][cg]);
      acc[g][cg] = mfma16<SWAP>(a1, w1, acc[g][cg]);
      acc[g][cg] = mfma16<SWAP>(a0, w2, acc[g][cg]);
    }
  }
#pragma unroll
  for (int g = 0; g < 4; g++)
#pragma unroll
    for (int r = 0; r < 4; r++) {
      double d = (double)acc[g][0][r] + (double)acc[g][1][r] +
                 (double)acc[g][2][r] + (double)acc[g][3][r];
      lred[(size_t)((g * 4 + mgrp) * 2 + ks) * 256 + (quad * 4 + r) * 16 + l15] = d;
    }
  __syncthreads();
  for (int u = tid; u < 1024; u += 512) {
    int b = u >> 4, cl = u & 15;
    int mg = b >> 4, rl = (b & 15) * 16 + cl;
    int gcol = hblk * 16 + cl;
    double gv[4];
#pragma unroll
    for (int g = 0; g < 4; g++)
      gv[g] = lred[(size_t)((g * 4 + mg) * 2 + 0) * 256 + rl] +
              lred[(size_t)((g * 4 + mg) * 2 + 1) * 256 + rl] +
              (double)bih[g * HID + gcol] + (double)bhh[g * HID + gcol];
    float i_ = 1.f / (1.f + expf(-(float)gv[0]));
    float f_ = 1.f / (1.f + expf(-(float)gv[1]));
    float g_ = tanhf((float)gv[2]);
    float o_ = 1.f / (1.f + expf(-(float)gv[3]));
    size_t ci = (size_t)b * HID + gcol;
    double cn = (double)f_ * cst[ci] + (double)i_ * (double)g_;
    cst[ci] = cn;
    float hn = o_ * tanhf((float)cn);
    u16 h0 = f2bf(hn); float r1 = hn - bf2f(h0);
    u16 h1 = f2bf(r1); float r2 = r1 - bf2f(h1);
    // swizzled write for next step's A operand
    int ks2 = gcol >> 9, c2 = (gcol >> 5) & 15, q2 = (gcol >> 3) & 3, j2 = gcol & 7;
    size_t oidx = (size_t)((ks2 * 16 + c2) * 4 + mg) * 512 + (q2 * 16 + (b & 15)) * 8 + j2;
    oh[oidx] = h0; om[oidx] = h1; ol[oidx] = f2bf(r2);
    hshi_t[ci] = h0; hslo_t[ci] = h1;   // row-major for logits GEMM
  }
}

__global__ void __launch_bounds__(512) k_step(
    const u32* __restrict__ flag,
    const u16* ah, const u16* am, const u16* al,
    const u16* xh, const u16* xm, const u16* xl,
    const u16* whhh, const u16* whhm, const u16* whhl,
    const u16* wihh, const u16* wihm, const u16* wihl,
    const float* bih, const float* bhh,
    double* cst, u16* hshi_t, u16* hslo_t, u16* oh, u16* om, u16* ol) {
  if (*flag) step_body<1>(ah, am, al, xh, xm, xl, whhh, whhm, whhl, wihh, wihm, wihl,
                          bih, bhh, cst, hshi_t, hslo_t, oh, om, ol);
  else       step_body<0>(ah, am, al, xh, xm, xl, whhh, whhm, whhl, wihh, wihm, wihl,
                          bih, bhh, cst, hshi_t, hslo_t, oh, om, ol);
}

// ---------------- logits GEMM, 3-product bf16x2 split, fused max/argmax/sumexp/label ----------------
template<int SWAP>
__device__ __forceinline__ void logits_body(
    const u16* __restrict__ hsh, const u16* __restrict__ hsl,
    const u16* __restrict__ wbh, const u16* __restrict__ wbl,
    const float* __restrict__ bout, const int* __restrict__ ids,
    u32* __restrict__ part, float* __restrict__ vlab) {
  __shared__ u16 lAh[128 * LDA];
  __shared__ u16 lAl[128 * LDA];
  __shared__ u16 lBh[128 * LDA];
  __shared__ u16 lBl[128 * LDA];
  const int tid = threadIdx.x;
  const int wave = tid >> 6, lane = tid & 63;
  const int quad = lane >> 4, l15 = lane & 15;
  const int wm = wave >> 1, wn = wave & 1;
  const int mtile = blockIdx.x, ntile = blockIdx.y;
  const size_t mbase = (size_t)mtile * 128, nbase = (size_t)ntile * 128;
  const int s0 = tid, s1 = tid + 256;
  const int r0 = s0 >> 2, c0 = (s0 & 3) * 8, r1 = s1 >> 2, c1 = (s1 & 3) * 8;
  const u16* gAh0 = hsh + (mbase + r0) * HID + c0;
  const u16* gAh1 = hsh + (mbase + r1) * HID + c1;
  const u16* gAl0 = hsl + (mbase + r0) * HID + c0;
  const u16* gAl1 = hsl + (mbase + r1) * HID + c1;
  const u16* gBh0 = wbh + (nbase + r0) * HID + c0;
  const u16* gBh1 = wbh + (nbase + r1) * HID + c1;
  const u16* gBl0 = wbl + (nbase + r0) * HID + c0;
  const u16* gBl1 = wbl + (nbase + r1) * HID + c1;
  f32x4 acc[4][4];
#pragma unroll
  for (int a = 0; a < 4; a++)
#pragma unroll
    for (int b = 0; b < 4; b++) acc[a][b] = (f32x4){0.f, 0.f, 0.f, 0.f};
  bf16x8 pAh0 = *(const bf16x8*)gAh0, pAh1 = *(const bf16x8*)gAh1;
  bf16x8 pAl0 = *(const bf16x8*)gAl0, pAl1 = *(const bf16x8*)gAl1;
  bf16x8 pBh0 = *(const bf16x8*)gBh0, pBh1 = *(const bf16x8*)gBh1;
  bf16x8 pBl0 = *(const bf16x8*)gBl0, pBl1 = *(const bf16x8*)gBl1;
  for (int k0 = 0; k0 < HID; k0 += 32) {
    __syncthreads();
    *(bf16x8*)&lAh[r0 * LDA + c0] = pAh0; *(bf16x8*)&lAh[r1 * LDA + c1] = pAh1;
    *(bf16x8*)&lAl[r0 * LDA + c0] = pAl0; *(bf16x8*)&lAl[r1 * LDA + c1] = pAl1;
    *(bf16x8*)&lBh[r0 * LDA + c0] = pBh0; *(bf16x8*)&lBh[r1 * LDA + c1] = pBh1;
    *(bf16x8*)&lBl[r0 * LDA + c0] = pBl0; *(bf16x8*)&lBl[r1 * LDA + c1] = pBl1;
    __syncthreads();
    if (k0 + 32 < HID) {
      int kn = k0 + 32;
      pAh0 = *(const bf16x8*)(gAh0 + kn); pAh1 = *(const bf16x8*)(gAh1 + kn);
      pAl0 = *(const bf16x8*)(gAl0 + kn); pAl1 = *(const bf16x8*)(gAl1 + kn);
      pBh0 = *(const bf16x8*)(gBh0 + kn); pBh1 = *(const bf16x8*)(gBh1 + kn);
      pBl0 = *(const bf16x8*)(gBl0 + kn); pBl1 = *(const bf16x8*)(gBl1 + kn);
    }
    bf16x8 afh[4], afl[4];
#pragma unroll
    for (int mt = 0; mt < 4; mt++) {
      int ab = (wm * 64 + mt * 16 + l15) * LDA + quad * 8;
      afh[mt] = *(const bf16x8*)&lAh[ab];
      afl[mt] = *(const bf16x8*)&lAl[ab];
    }
#pragma unroll
    for (int nt = 0; nt < 4; nt++) {
      int nb = (wn * 64 + nt * 16 + l15) * LDA + quad * 8;
      bf16x8 bh = *(const bf16x8*)&lBh[nb];
      bf16x8 bl = *(const bf16x8*)&lBl[nb];
#pragma unroll
      for (int mt = 0; mt < 4; mt++) {
        acc[mt][nt] = mfma16<SWAP>(afh[mt], bh, acc[mt][nt]);
        acc[mt][nt] = mfma16<SWAP>(afl[mt], bh, acc[mt][nt]);
        acc[mt][nt] = mfma16<SWAP>(afh[mt], bl, acc[mt][nt]);
      }
    }
  }
  __syncthreads();
  // ---- epilogue ----
  float bo[4];
#pragma unroll
  for (int nt = 0; nt < 4; nt++) bo[nt] = bout[nbase + wn * 64 + nt * 16 + l15];
#pragma unroll
  for (int mt = 0; mt < 4; mt++)
#pragma unroll
    for (int nt = 0; nt < 4; nt++)
#pragma unroll
      for (int r = 0; r < 4; r++) acc[mt][nt][r] += bo[nt];
  float* sv = (float*)lAh;   // [wave][64] per-half row max
  int*   sc = (int*)lAl;     // [wave][64] per-half row argmax col
  float* ss = (float*)lBh;   // [wave][64] per-half row sumexp
  float tval[4][4]; int tcol[4][4]; float se[4][4];
#pragma unroll
  for (int mt = 0; mt < 4; mt++)
#pragma unroll
    for (int r = 0; r < 4; r++) {
      float bv = acc[mt][0][r];
      int bc = (int)nbase + wn * 64 + l15;
#pragma unroll
      for (int nt = 1; nt < 4; nt++) {
        float v = acc[mt][nt][r];
        int c = (int)nbase + wn * 64 + nt * 16 + l15;
        if (v > bv || (v == bv && c < bc)) { bv = v; bc = c; }
      }
#pragma unroll
      for (int d = 1; d < 16; d <<= 1) {
        float ov = __shfl_xor(bv, d);
        int oc = __shfl_xor(bc, d);
        if (ov > bv || (ov == bv && oc < bc)) { bv = ov; bc = oc; }
      }
      if (l15 == 0) {
        sv[wave * 64 + mt * 16 + quad * 4 + r] = bv;
        sc[wave * 64 + mt * 16 + quad * 4 + r] = bc;
      }
    }
  __syncthreads();
#pragma unroll
  for (int mt = 0; mt < 4; mt++)
#pragma unroll
    for (int r = 0; r < 4; r++) {
      int rl = mt * 16 + quad * 4 + r;
      float mv = sv[wave * 64 + rl]; int mc = sc[wave * 64 + rl];
      float ov = sv[(wave ^ 1) * 64 + rl]; int oc = sc[(wave ^ 1) * 64 + rl];
      if (ov > mv || (ov == mv && oc < mc)) { mv = ov; mc = oc; }
      tval[mt][r] = mv; tcol[mt][r] = mc;
    }
#pragma unroll
  for (int mt = 0; mt < 4; mt++)
#pragma unroll
    for (int r = 0; r < 4; r++) {
      float tm = tval[mt][r];
      float s = 0.f;
#pragma unroll
      for (int nt = 0; nt < 4; nt++) s += __expf(acc[mt][nt][r] - tm);
#pragma unroll
      for (int d = 1; d < 16; d <<= 1) s += __shfl_xor(s, d);
      se[mt][r] = s;
      int row_g = (int)mbase + wm * 64 + mt * 16 + quad * 4 + r;
      if (row_g < ROWS) {
        int lab = ids[row_g + 64];
        int cb = lab - (int)nbase - wn * 64;
        if (cb >= 0 && cb < 64 && (cb & 15) == l15) {
          int ntl = cb >> 4;
          float v = acc[mt][0][r];
#pragma unroll
          for (int nt = 1; nt < 4; nt++) if (ntl == nt) v = acc[mt][nt][r];
          vlab[row_g] = v;
        }
      }
    }
#pragma unroll
  for (int mt = 0; mt < 4; mt++)
#pragma unroll
    for (int r = 0; r < 4; r++)
      if (l15 == 0) ss[wave * 64 + mt * 16 + quad * 4 + r] = se[mt][r];
  __syncthreads();
#pragma unroll
  for (int mt = 0; mt < 4; mt++)
#pragma unroll
    for (int r = 0; r < 4; r++) {
      int rl = mt * 16 + quad * 4 + r;
      int row_g = (int)mbase + wm * 64 + rl;
      if (row_g < ROWS && l15 == 0 && wn == 0) {
        u32* p = part + ((size_t)row_g * NTILE + ntile) * 3;
        p[0] = __float_as_uint(tval[mt][r]);
        p[1] = (u32)tcol[mt][r];
        p[2] = __float_as_uint(se[mt][r] + ss[(wave ^ 1) * 64 + rl]);
      }
    }
}

__global__ void __launch_bounds__(256, 3) k_logits(
    const u32* __restrict__ flag,
    const u16* hsh, const u16* hsl, const u16* wbh, const u16* wbl,
    const float* bout, const int* ids, u32* part, float* vlab) {
  if (*flag) logits_body<1>(hsh, hsl, wbh, wbl, bout, ids, part, vlab);
  else       logits_body<0>(hsh, hsl, wbh, wbl, bout, ids, part, vlab);
}

// ---------------- per-row merge: global argmax + logsumexp + loss ----------------
__global__ void __launch_bounds__(64) k_rowred(
    const u32* __restrict__ part, const float* __restrict__ vlab,
    const int* __restrict__ ids, float* __restrict__ losst, float* __restrict__ dout) {
  int r = blockIdx.x, lane = threadIdx.x;
  float m = -3e38f, s = 0.f;
  int c = 0x7FFFFFFF;
  for (int i = lane; i < NTILE; i += 64) {
    const u32* p = part + ((size_t)r * NTILE + i) * 3;
    float tv = __uint_as_float(p[0]);
    int tc = (int)p[1];
    float ts = __uint_as_float(p[2]);
    if (tv > m || (tv == m && tc < c)) c = tc;
    float nm = fmaxf(m, tv);
    s = s * __expf(m - nm) + ts * __expf(tv - nm);
    m = nm;
  }
#pragma unroll
  for (int d = 1; d < 64; d <<= 1) {
    float om = __shfl_xor(m, d);
    int oc = __shfl_xor(c, d);
    float os = __shfl_xor(s, d);
    if (om > m || (om == m && oc < c)) c = oc;
    float nm = fmaxf(m, om);
    s = s * __expf(m - nm) + os * __expf(om - nm);
    m = nm;
  }
  if (lane == 0) {
    dout[1 + 64 + r] = (float)c;
    int lab = ids[r + 64];
    if (lab != 0) atomicAdd(&losst[r >> 6], (m + __logf(s)) - vlab[r]);
  }
}

// ---------------- finalize ----------------
__global__ void __launch_bounds__(64) k_final(
    const float* __restrict__ losst, const int* __restrict__ ids, float* __restrict__ dout) {
  int lane = threadIdx.x;
  dout[1 + lane] = 1.0f;
  float v = 0.f;
  if (lane < NSTEP) {
    int cnz = 0;
    for (int b2 = 0; b2 < BB; b2++) cnz += (ids[(lane + 1) * BB + b2] != 0);
    v = losst[lane] / (float)max(cnz, 1);
  }
#pragma unroll
  for (int d = 32; d > 0; d >>= 1) v += __shfl_down(v, d);
  if (lane == 0) dout[0] = v;
}

// ---------------- host ----------------
extern "C" void kernel_launch(void* const* d_in, const int* in_sizes, int n_in,
                              void* d_out, int out_size, void* d_ws, size_t ws_size,
                              hipStream_t stream) {
  (void)in_sizes; (void)n_in; (void)out_size; (void)ws_size;
  const int* ids = (const int*)d_in[0];
  const float* hid0 = (const float*)d_in[3];
  const float* cel0 = (const float*)d_in[4];
  const float* emb = (const float*)d_in[5];
  const float* wih = (const float*)d_in[6];
  const float* whh = (const float*)d_in[7];
  const float* bih = (const float*)d_in[8];
  const float* bhh = (const float*)d_in[9];
  const float* wout = (const float*)d_in[10];
  const float* bout = (const float*)d_in[11];
  float* out = (float*)d_out;

  char* ws = (char*)d_ws;
  u16* wbh     = (u16*)(ws + 0ull);            //  65,536,000
  u16* wbl     = (u16*)(ws + 65536000ull);     //  65,536,000
  u16* whh_h   = (u16*)(ws + 131072000ull);    //   8,388,608
  u16* whh_m   = (u16*)(ws + 139460608ull);
  u16* whh_l   = (u16*)(ws + 147849216ull);
  u16* wih_h   = (u16*)(ws + 156237824ull);    //   4,194,304
  u16* wih_m   = (u16*)(ws + 160432128ull);
  u16* wih_l   = (u16*)(ws + 164626432ull);
  u16* xs_h    = (u16*)(ws + 168820736ull);    //   4,128,768
  u16* xs_m    = (u16*)(ws + 172949504ull);
  u16* xs_l    = (u16*)(ws + 177078272ull);
  u16* hs_hi   = (u16*)(ws + 181207040ull);    //   8,388,608 (4096 rows padded)
  u16* hs_lo   = (u16*)(ws + 189595648ull);    //   8,388,608
  u16* pp      = (u16*)(ws + 197984256ull);    //     786,432
  double* cst  = (double*)(ws + 198770688ull); //     524,288
  u32* part    = (u32*)(ws + 199294976ull);    //  12,096,000
  float* vlab  = (float*)(ws + 211390976ull);  //      16,128
  float* losst = (float*)(ws + 211407104ull);  //         256
  u32* flag    = (u32*)(ws + 211407360ull);    //           4

  const size_t HB = (size_t)BB * HID;
  u16* pp0h = pp;            u16* pp0m = pp + HB;     u16* pp0l = pp + 2 * HB;
  u16* pp1h = pp + 3 * HB;   u16* pp1m = pp + 4 * HB; u16* pp1l = pp + 5 * HB;

  k_probe<<<1, 64, 0, stream>>>(flag);
  k_prep_w<<<4096, 256, 0, stream>>>(wout, whh, wih, wbh, wbl,
                                     whh_h, whh_m, whh_l, wih_h, wih_m, wih_l);
  k_prep_x<<<2048, 256, 0, stream>>>(ids, emb, hid0, cel0, xs_h, xs_m, xs_l,
                                     pp0h, pp0m, pp0l, cst, hs_hi, hs_lo, losst);
  for (int t = 0; t < NSTEP; t++) {
    const u16* iah = (t & 1) ? pp1h : pp0h;
    const u16* iam = (t & 1) ? pp1m : pp0m;
    const u16* ial = (t & 1) ? pp1l : pp0l;
    u16* oah = (t & 1) ? pp0h : pp1h;
    u16* oam = (t & 1) ? pp0m : pp1m;
    u16* oal = (t & 1) ? pp0l : pp1l;
    k_step<<<64, 512, 0, stream>>>(flag, iah, iam, ial,
        xs_h + (size_t)t * BB * EMB, xs_m + (size_t)t * BB * EMB, xs_l + (size_t)t * BB * EMB,
        whh_h, whh_m, whh_l, wih_h, wih_m, wih_l, bih, bhh, cst,
        hs_hi + (size_t)t * HB, hs_lo + (size_t)t * HB, oah, oam, oal);
  }
  k_logits<<<dim3(32, 250), 256, 0, stream>>>(flag, hs_hi, hs_lo, wbh, wbl, bout, ids, part, vlab);
  k_rowred<<<ROWS, 64, 0, stream>>>(part, vlab, ids, losst, out);
  k_final<<<1, 64, 0, stream>>>(losst, ids, out);
}

// Round 5
// 2471.937 us; speedup vs baseline: 2.8126x; 1.9919x over previous
//
#include <hip/hip_runtime.h>
#include <stdint.h>
#include <stddef.h>

#define VOC 32000
#define EMB 512
#define HID 1024
#define BB 64
#define NSTEP 63
#define ROWS 4032
#define ROWSP 4096
#define NTILE 250
#define LDA 40   // k_logits LDS row stride (elements)

typedef unsigned short u16;
typedef unsigned int u32;
typedef unsigned long long u64;
typedef __attribute__((ext_vector_type(8))) short bf16x8;
typedef __attribute__((ext_vector_type(4))) float f32x4;

__device__ __forceinline__ u16 f2bf(float f) {
  u32 u = __float_as_uint(f);
  return (u16)((u + 0x7FFFu + ((u >> 16) & 1u)) >> 16);
}
__device__ __forceinline__ float bf2f(u16 h) { return __uint_as_float(((u32)h) << 16); }

template<int SWAP>
__device__ __forceinline__ f32x4 mfma16(bf16x8 a, bf16x8 b, f32x4 c) {
  if (SWAP) return __builtin_amdgcn_mfma_f32_16x16x32_bf16(b, a, c, 0, 0, 0);
  return __builtin_amdgcn_mfma_f32_16x16x32_bf16(a, b, c, 0, 0, 0);
}

// ---------------- probe: resolve MFMA operand convention at runtime ----------------
__global__ void k_probe(u32* flag) {
  int lane = threadIdx.x & 63;
  int quad = lane >> 4, l15 = lane & 15;
  bf16x8 a, b;
#pragma unroll
  for (int j = 0; j < 8; j++) {
    int k = quad * 8 + j;
    a[j] = (short)f2bf(k == l15 ? 1.0f : 0.0f);
    b[j] = (short)f2bf((float)(l15 + 3));
  }
  f32x4 c = {0.f, 0.f, 0.f, 0.f};
  c = __builtin_amdgcn_mfma_f32_16x16x32_bf16(a, b, c, 0, 0, 0);
  if (threadIdx.x == 1) *flag = (c[0] == 3.0f) ? 1u : 0u;
}

// ---------------- weight prep ----------------
// W_out -> (hi,lo) row-major.
// W_hh & W_ih -> combined 3-way split, per-block fragment order:
//   group G = (b*48 + c)*64 + lane; element G*8+j.
//   lane = quad*16 + l15; vc = l15: g = vc>>2, jc = vc&3; weight row = g*1024 + b*4 + jc.
//   c<32: k = c*32 + quad*8 + j (from W_hh, K=1024); c>=32: k' = (c-32)*32 + quad*8 + j (W_ih, K=512).
__global__ void __launch_bounds__(256) k_prep_w(
    const float* __restrict__ wout, const float* __restrict__ whh, const float* __restrict__ wih,
    u16* __restrict__ wbh, u16* __restrict__ wbl,
    u16* __restrict__ w3h, u16* __restrict__ w3m, u16* __restrict__ w3l) {
  size_t i0 = (size_t)blockIdx.x * blockDim.x + threadIdx.x;
  size_t stride = (size_t)gridDim.x * blockDim.x;
  for (size_t j = i0; j < (size_t)VOC * HID; j += stride) {
    float v = wout[j];
    u16 h = f2bf(v);
    wbh[j] = h; wbl[j] = f2bf(v - bf2f(h));
  }
  for (size_t G = i0; G < 786432; G += stride) {   // 256 blocks * 48 chunks * 64 lanes
    int b = (int)(G / 3072);
    int rem = (int)(G - (size_t)b * 3072);
    int c = rem >> 6, lane = rem & 63;
    int l15 = lane & 15, quad = lane >> 4;
    int g = l15 >> 2, jc = l15 & 3;
    int row = g * 1024 + b * 4 + jc;
    const float* src = (c < 32) ? (whh + (size_t)row * HID + c * 32 + quad * 8)
                                : (wih + (size_t)row * EMB + (c - 32) * 32 + quad * 8);
    bf16x8 vh, vm, vl;
#pragma unroll
    for (int j = 0; j < 8; j++) {
      float v = src[j];
      u16 h = f2bf(v); float r1 = v - bf2f(h);
      u16 m = f2bf(r1); float r2 = r1 - bf2f(m);
      vh[j] = (short)h; vm[j] = (short)m; vl[j] = (short)f2bf(r2);
    }
    *(bf16x8*)(w3h + G * 8) = vh;
    *(bf16x8*)(w3m + G * 8) = vm;
    *(bf16x8*)(w3l + G * 8) = vl;
  }
}

// ---------------- input prep ----------------
// Activation fragment order (per k-chunk c, wave w): offset = ((c*4+w)<<9) + lane*8 + j
//   <-> (batch = w*16 + (lane&15), k = c*32 + (lane>>4)*8 + j).
__global__ void __launch_bounds__(256) k_prep_x(
    const int* __restrict__ ids, const float* __restrict__ emb,
    const float* __restrict__ h0src, const float* __restrict__ c0src,
    const float* __restrict__ bih, const float* __restrict__ bhh,
    u16* __restrict__ xh, u16* __restrict__ xm, u16* __restrict__ xl,
    u16* __restrict__ h0h, u16* __restrict__ h0m, u16* __restrict__ h0l,
    double* __restrict__ cst, double* __restrict__ bsum,
    u16* __restrict__ hshi, u16* __restrict__ hslo, float* __restrict__ losst) {
  size_t i0 = (size_t)blockIdx.x * blockDim.x + threadIdx.x;
  size_t stride = (size_t)gridDim.x * blockDim.x;
  for (size_t G = i0; G < 258048; G += stride) {   // 63 * 16 * 4 * 64
    int lane = (int)(G & 63), w = (int)((G >> 6) & 3);
    int cx = (int)((G >> 8) & 15), t = (int)(G >> 12);
    int batch = w * 16 + (lane & 15);
    int k = cx * 32 + (lane >> 4) * 8;
    int id = ids[t * 64 + batch];
    size_t dst = (size_t)t * 32768 + (size_t)((cx * 4 + w) << 9) + lane * 8;
    bf16x8 vh, vm, vl;
#pragma unroll
    for (int j = 0; j < 8; j++) {
      float v = emb[(size_t)id * EMB + k + j];
      u16 h = f2bf(v); float r1 = v - bf2f(h);
      u16 m = f2bf(r1); float r2 = r1 - bf2f(m);
      vh[j] = (short)h; vm[j] = (short)m; vl[j] = (short)f2bf(r2);
    }
    *(bf16x8*)(xh + dst) = vh;
    *(bf16x8*)(xm + dst) = vm;
    *(bf16x8*)(xl + dst) = vl;
  }
  for (size_t G = i0; G < 8192; G += stride) {     // 32 * 4 * 64
    int lane = (int)(G & 63), w = (int)((G >> 6) & 3), c = (int)(G >> 8);
    int batch = w * 16 + (lane & 15);
    int k = c * 32 + (lane >> 4) * 8;
    size_t dst = (size_t)((c * 4 + w) << 9) + lane * 8;
    bf16x8 vh, vm, vl;
#pragma unroll
    for (int j = 0; j < 8; j++) {
      float v = h0src[(size_t)batch * HID + k + j];
      u16 h = f2bf(v); float r1 = v - bf2f(h);
      u16 m = f2bf(r1); float r2 = r1 - bf2f(m);
      vh[j] = (short)h; vm[j] = (short)m; vl[j] = (short)f2bf(r2);
    }
    *(bf16x8*)(h0h + dst) = vh;
    *(bf16x8*)(h0m + dst) = vm;
    *(bf16x8*)(h0l + dst) = vl;
  }
  for (size_t i = i0; i < 65536; i += stride) {    // cst lane-linear: b,wv,l
    int b = (int)(i >> 8), wv = (int)((i >> 6) & 3), l = (int)(i & 63);
    int batch = wv * 16 + (l & 15);
    int h = b * 4 + (l >> 4);
    cst[i] = (double)c0src[(size_t)batch * HID + h];
  }
  for (size_t i = i0; i < 4096; i += stride) bsum[i] = (double)bih[i] + (double)bhh[i];
  for (size_t j = i0; j < (size_t)(ROWSP - ROWS) * HID; j += stride) {
    hshi[(size_t)ROWS * HID + j] = 0;
    hslo[(size_t)ROWS * HID + j] = 0;
  }
  if (i0 < 64) losst[i0] = 0.f;
}

// ---------------- LSTM step: 256 blocks x 256 thr; block = 4 h-units x 4 gates ----------------
template<int SWAP>
__device__ __forceinline__ void step_body(
    const u16* __restrict__ ah, const u16* __restrict__ am, const u16* __restrict__ al,
    const u16* __restrict__ xh, const u16* __restrict__ xm, const u16* __restrict__ xl,
    const u16* __restrict__ w3h, const u16* __restrict__ w3m, const u16* __restrict__ w3l,
    const double* __restrict__ bsum, double* __restrict__ cst,
    u16* __restrict__ hshi_t, u16* __restrict__ hslo_t,
    u16* __restrict__ oh, u16* __restrict__ om, u16* __restrict__ ol) {
  __shared__ double gd[4][256];
  const int tid = threadIdx.x;
  const int wave = tid >> 6, lane = tid & 63;
  const int quad = lane >> 4, l15 = lane & 15;
  const int b = blockIdx.x;
  const size_t wbase = (size_t)b * 24576;   // 48 chunks * 64 lanes * 8
  f32x4 acc[4];
#pragma unroll
  for (int cg = 0; cg < 4; cg++) acc[cg] = (f32x4){0.f, 0.f, 0.f, 0.f};
#pragma unroll 4
  for (int c = 0; c < 32; c++) {
    size_t woff = wbase + (size_t)c * 512 + lane * 8;
    size_t aoff = (size_t)((c * 4 + wave) << 9) + lane * 8;
    bf16x8 a0 = *(const bf16x8*)(ah + aoff);
    bf16x8 a1 = *(const bf16x8*)(am + aoff);
    bf16x8 a2 = *(const bf16x8*)(al + aoff);
    bf16x8 w0 = *(const bf16x8*)(w3h + woff);
    bf16x8 w1 = *(const bf16x8*)(w3m + woff);
    bf16x8 w2 = *(const bf16x8*)(w3l + woff);
    int cg = c & 3;
    acc[cg] = mfma16<SWAP>(a0, w0, acc[cg]);
    acc[cg] = mfma16<SWAP>(a1, w0, acc[cg]);
    acc[cg] = mfma16<SWAP>(a0, w1, acc[cg]);
    acc[cg] = mfma16<SWAP>(a2, w0, acc[cg]);
    acc[cg] = mfma16<SWAP>(a1, w1, acc[cg]);
    acc[cg] = mfma16<SWAP>(a0, w2, acc[cg]);
  }
#pragma unroll 4
  for (int cx = 0; cx < 16; cx++) {
    size_t woff = wbase + (size_t)(32 + cx) * 512 + lane * 8;
    size_t aoff = (size_t)((cx * 4 + wave) << 9) + lane * 8;
    bf16x8 a0 = *(const bf16x8*)(xh + aoff);
    bf16x8 a1 = *(const bf16x8*)(xm + aoff);
    bf16x8 a2 = *(const bf16x8*)(xl + aoff);
    bf16x8 w0 = *(const bf16x8*)(w3h + woff);
    bf16x8 w1 = *(const bf16x8*)(w3m + woff);
    bf16x8 w2 = *(const bf16x8*)(w3l + woff);
    int cg = cx & 3;
    acc[cg] = mfma16<SWAP>(a0, w0, acc[cg]);
    acc[cg] = mfma16<SWAP>(a1, w0, acc[cg]);
    acc[cg] = mfma16<SWAP>(a0, w1, acc[cg]);
    acc[cg] = mfma16<SWAP>(a2, w0, acc[cg]);
    acc[cg] = mfma16<SWAP>(a1, w1, acc[cg]);
    acc[cg] = mfma16<SWAP>(a0, w2, acc[cg]);
  }
  // fp64 combine + bias; D layout: batch_local = quad*4+r, vc = l15
  double bsv = bsum[(l15 >> 2) * 1024 + b * 4 + (l15 & 3)];
#pragma unroll
  for (int r = 0; r < 4; r++) {
    double v = (double)acc[0][r] + (double)acc[1][r] +
               (double)acc[2][r] + (double)acc[3][r] + bsv;
    gd[wave][(quad * 4 + r) * 16 + l15] = v;
  }
  __syncthreads();
  // cell update: lane -> (batch_local = lane&15, j = lane>>4)
  {
    int bl = lane & 15, j = lane >> 4;
    double gi = gd[wave][bl * 16 + 0 * 4 + j];
    double gf = gd[wave][bl * 16 + 1 * 4 + j];
    double gg = gd[wave][bl * 16 + 2 * 4 + j];
    double go = gd[wave][bl * 16 + 3 * 4 + j];
    float i_ = 1.f / (1.f + expf(-(float)gi));
    float f_ = 1.f / (1.f + expf(-(float)gf));
    float g_ = tanhf((float)gg);
    float o_ = 1.f / (1.f + expf(-(float)go));
    int cidx = b * 256 + wave * 64 + lane;
    double cn = (double)f_ * cst[cidx] + (double)i_ * (double)g_;
    cst[cidx] = cn;
    float hn = o_ * tanhf((float)cn);
    u16 h0 = f2bf(hn); float r1 = hn - bf2f(h0);
    u16 h1 = f2bf(r1); float r2 = r1 - bf2f(h1);
    int batch = wave * 16 + bl;
    int h = b * 4 + j;
    int c2 = h >> 5, quad2 = (h >> 3) & 3, j2 = h & 7;
    size_t oidx = (size_t)((c2 * 4 + wave) << 9) + ((quad2 * 16 + bl) << 3) + j2;
    oh[oidx] = h0; om[oidx] = h1; ol[oidx] = f2bf(r2);
    hshi_t[(size_t)batch * HID + h] = h0;
    hslo_t[(size_t)batch * HID + h] = h1;
  }
}

__global__ void __launch_bounds__(256) k_step(
    const u32* __restrict__ flag,
    const u16* ah, const u16* am, const u16* al,
    const u16* xh, const u16* xm, const u16* xl,
    const u16* w3h, const u16* w3m, const u16* w3l,
    const double* bsum, double* cst,
    u16* hshi_t, u16* hslo_t, u16* oh, u16* om, u16* ol) {
  if (*flag) step_body<1>(ah, am, al, xh, xm, xl, w3h, w3m, w3l, bsum, cst, hshi_t, hslo_t, oh, om, ol);
  else       step_body<0>(ah, am, al, xh, xm, xl, w3h, w3m, w3l, bsum, cst, hshi_t, hslo_t, oh, om, ol);
}

// ---------------- logits GEMM, 3-product bf16x2 split, fused max/argmax/sumexp/label ----------------
template<int SWAP>
__device__ __forceinline__ void logits_body(
    const u16* __restrict__ hsh, const u16* __restrict__ hsl,
    const u16* __restrict__ wbh, const u16* __restrict__ wbl,
    const float* __restrict__ bout, const int* __restrict__ ids,
    u32* __restrict__ part, float* __restrict__ vlab) {
  __shared__ u16 lAh[128 * LDA];
  __shared__ u16 lAl[128 * LDA];
  __shared__ u16 lBh[128 * LDA];
  __shared__ u16 lBl[128 * LDA];
  const int tid = threadIdx.x;
  const int wave = tid >> 6, lane = tid & 63;
  const int quad = lane >> 4, l15 = lane & 15;
  const int wm = wave >> 1, wn = wave & 1;
  const int mtile = blockIdx.x, ntile = blockIdx.y;
  const size_t mbase = (size_t)mtile * 128, nbase = (size_t)ntile * 128;
  const int s0 = tid, s1 = tid + 256;
  const int r0 = s0 >> 2, c0 = (s0 & 3) * 8, r1 = s1 >> 2, c1 = (s1 & 3) * 8;
  const u16* gAh0 = hsh + (mbase + r0) * HID + c0;
  const u16* gAh1 = hsh + (mbase + r1) * HID + c1;
  const u16* gAl0 = hsl + (mbase + r0) * HID + c0;
  const u16* gAl1 = hsl + (mbase + r1) * HID + c1;
  const u16* gBh0 = wbh + (nbase + r0) * HID + c0;
  const u16* gBh1 = wbh + (nbase + r1) * HID + c1;
  const u16* gBl0 = wbl + (nbase + r0) * HID + c0;
  const u16* gBl1 = wbl + (nbase + r1) * HID + c1;
  f32x4 acc[4][4];
#pragma unroll
  for (int a = 0; a < 4; a++)
#pragma unroll
    for (int b = 0; b < 4; b++) acc[a][b] = (f32x4){0.f, 0.f, 0.f, 0.f};
  bf16x8 pAh0 = *(const bf16x8*)gAh0, pAh1 = *(const bf16x8*)gAh1;
  bf16x8 pAl0 = *(const bf16x8*)gAl0, pAl1 = *(const bf16x8*)gAl1;
  bf16x8 pBh0 = *(const bf16x8*)gBh0, pBh1 = *(const bf16x8*)gBh1;
  bf16x8 pBl0 = *(const bf16x8*)gBl0, pBl1 = *(const bf16x8*)gBl1;
  for (int k0 = 0; k0 < HID; k0 += 32) {
    __syncthreads();
    *(bf16x8*)&lAh[r0 * LDA + c0] = pAh0; *(bf16x8*)&lAh[r1 * LDA + c1] = pAh1;
    *(bf16x8*)&lAl[r0 * LDA + c0] = pAl0; *(bf16x8*)&lAl[r1 * LDA + c1] = pAl1;
    *(bf16x8*)&lBh[r0 * LDA + c0] = pBh0; *(bf16x8*)&lBh[r1 * LDA + c1] = pBh1;
    *(bf16x8*)&lBl[r0 * LDA + c0] = pBl0; *(bf16x8*)&lBl[r1 * LDA + c1] = pBl1;
    __syncthreads();
    if (k0 + 32 < HID) {
      int kn = k0 + 32;
      pAh0 = *(const bf16x8*)(gAh0 + kn); pAh1 = *(const bf16x8*)(gAh1 + kn);
      pAl0 = *(const bf16x8*)(gAl0 + kn); pAl1 = *(const bf16x8*)(gAl1 + kn);
      pBh0 = *(const bf16x8*)(gBh0 + kn); pBh1 = *(const bf16x8*)(gBh1 + kn);
      pBl0 = *(const bf16x8*)(gBl0 + kn); pBl1 = *(const bf16x8*)(gBl1 + kn);
    }
    bf16x8 afh[4], afl[4];
#pragma unroll
    for (int mt = 0; mt < 4; mt++) {
      int ab = (wm * 64 + mt * 16 + l15) * LDA + quad * 8;
      afh[mt] = *(const bf16x8*)&lAh[ab];
      afl[mt] = *(const bf16x8*)&lAl[ab];
    }
#pragma unroll
    for (int nt = 0; nt < 4; nt++) {
      int nb = (wn * 64 + nt * 16 + l15) * LDA + quad * 8;
      bf16x8 bh = *(const bf16x8*)&lBh[nb];
      bf16x8 bl = *(const bf16x8*)&lBl[nb];
#pragma unroll
      for (int mt = 0; mt < 4; mt++) {
        acc[mt][nt] = mfma16<SWAP>(afh[mt], bh, acc[mt][nt]);
        acc[mt][nt] = mfma16<SWAP>(afl[mt], bh, acc[mt][nt]);
        acc[mt][nt] = mfma16<SWAP>(afh[mt], bl, acc[mt][nt]);
      }
    }
  }
  __syncthreads();
  // ---- epilogue ----
  float bo[4];
#pragma unroll
  for (int nt = 0; nt < 4; nt++) bo[nt] = bout[nbase + wn * 64 + nt * 16 + l15];
#pragma unroll
  for (int mt = 0; mt < 4; mt++)
#pragma unroll
    for (int nt = 0; nt < 4; nt++)
#pragma unroll
      for (int r = 0; r < 4; r++) acc[mt][nt][r] += bo[nt];
  float* sv = (float*)lAh;
  int*   sc = (int*)lAl;
  float* ss = (float*)lBh;
  float tval[4][4]; int tcol[4][4]; float se[4][4];
#pragma unroll
  for (int mt = 0; mt < 4; mt++)
#pragma unroll
    for (int r = 0; r < 4; r++) {
      float bv = acc[mt][0][r];
      int bc = (int)nbase + wn * 64 + l15;
#pragma unroll
      for (int nt = 1; nt < 4; nt++) {
        float v = acc[mt][nt][r];
        int c = (int)nbase + wn * 64 + nt * 16 + l15;
        if (v > bv || (v == bv && c < bc)) { bv = v; bc = c; }
      }
#pragma unroll
      for (int d = 1; d < 16; d <<= 1) {
        float ov = __shfl_xor(bv, d);
        int oc = __shfl_xor(bc, d);
        if (ov > bv || (ov == bv && oc < bc)) { bv = ov; bc = oc; }
      }
      if (l15 == 0) {
        sv[wave * 64 + mt * 16 + quad * 4 + r] = bv;
        sc[wave * 64 + mt * 16 + quad * 4 + r] = bc;
      }
    }
  __syncthreads();
#pragma unroll
  for (int mt = 0; mt < 4; mt++)
#pragma unroll
    for (int r = 0; r < 4; r++) {
      int rl = mt * 16 + quad * 4 + r;
      float mv = sv[wave * 64 + rl]; int mc = sc[wave * 64 + rl];
      float ov = sv[(wave ^ 1) * 64 + rl]; int oc = sc[(wave ^ 1) * 64 + rl];
      if (ov > mv || (ov == mv && oc < mc)) { mv = ov; mc = oc; }
      tval[mt][r] = mv; tcol[mt][r] = mc;
    }
#pragma unroll
  for (int mt = 0; mt < 4; mt++)
#pragma unroll
    for (int r = 0; r < 4; r++) {
      float tm = tval[mt][r];
      float s = 0.f;
#pragma unroll
      for (int nt = 0; nt < 4; nt++) s += __expf(acc[mt][nt][r] - tm);
#pragma unroll
      for (int d = 1; d < 16; d <<= 1) s += __shfl_xor(s, d);
      se[mt][r] = s;
      int row_g = (int)mbase + wm * 64 + mt * 16 + quad * 4 + r;
      if (row_g < ROWS) {
        int lab = ids[row_g + 64];
        int cb = lab - (int)nbase - wn * 64;
        if (cb >= 0 && cb < 64 && (cb & 15) == l15) {
          int ntl = cb >> 4;
          float v = acc[mt][0][r];
#pragma unroll
          for (int nt = 1; nt < 4; nt++) if (ntl == nt) v = acc[mt][nt][r];
          vlab[row_g] = v;
        }
      }
    }
#pragma unroll
  for (int mt = 0; mt < 4; mt++)
#pragma unroll
    for (int r = 0; r < 4; r++)
      if (l15 == 0) ss[wave * 64 + mt * 16 + quad * 4 + r] = se[mt][r];
  __syncthreads();
#pragma unroll
  for (int mt = 0; mt < 4; mt++)
#pragma unroll
    for (int r = 0; r < 4; r++) {
      int rl = mt * 16 + quad * 4 + r;
      int row_g = (int)mbase + wm * 64 + rl;
      if (row_g < ROWS && l15 == 0 && wn == 0) {
        u32* p = part + ((size_t)row_g * NTILE + ntile) * 3;
        p[0] = __float_as_uint(tval[mt][r]);
        p[1] = (u32)tcol[mt][r];
        p[2] = __float_as_uint(se[mt][r] + ss[(wave ^ 1) * 64 + rl]);
      }
    }
}

__global__ void __launch_bounds__(256, 3) k_logits(
    const u32* __restrict__ flag,
    const u16* hsh, const u16* hsl, const u16* wbh, const u16* wbl,
    const float* bout, const int* ids, u32* part, float* vlab) {
  if (*flag) logits_body<1>(hsh, hsl, wbh, wbl, bout, ids, part, vlab);
  else       logits_body<0>(hsh, hsl, wbh, wbl, bout, ids, part, vlab);
}

// ---------------- per-row merge: global argmax + logsumexp + loss ----------------
__global__ void __launch_bounds__(64) k_rowred(
    const u32* __restrict__ part, const float* __restrict__ vlab,
    const int* __restrict__ ids, float* __restrict__ losst, float* __restrict__ dout) {
  int r = blockIdx.x, lane = threadIdx.x;
  float m = -3e38f, s = 0.f;
  int c = 0x7FFFFFFF;
  for (int i = lane; i < NTILE; i += 64) {
    const u32* p = part + ((size_t)r * NTILE + i) * 3;
    float tv = __uint_as_float(p[0]);
    int tc = (int)p[1];
    float ts = __uint_as_float(p[2]);
    if (tv > m || (tv == m && tc < c)) c = tc;
    float nm = fmaxf(m, tv);
    s = s * __expf(m - nm) + ts * __expf(tv - nm);
    m = nm;
  }
#pragma unroll
  for (int d = 1; d < 64; d <<= 1) {
    float om = __shfl_xor(m, d);
    int oc = __shfl_xor(c, d);
    float os = __shfl_xor(s, d);
    if (om > m || (om == m && oc < c)) c = oc;
    float nm = fmaxf(m, om);
    s = s * __expf(m - nm) + os * __expf(om - nm);
    m = nm;
  }
  if (lane == 0) {
    dout[1 + 64 + r] = (float)c;
    int lab = ids[r + 64];
    if (lab != 0) atomicAdd(&losst[r >> 6], (m + __logf(s)) - vlab[r]);
  }
}

// ---------------- finalize ----------------
__global__ void __launch_bounds__(64) k_final(
    const float* __restrict__ losst, const int* __restrict__ ids, float* __restrict__ dout) {
  int lane = threadIdx.x;
  dout[1 + lane] = 1.0f;
  float v = 0.f;
  if (lane < NSTEP) {
    int cnz = 0;
    for (int b2 = 0; b2 < BB; b2++) cnz += (ids[(lane + 1) * BB + b2] != 0);
    v = losst[lane] / (float)max(cnz, 1);
  }
#pragma unroll
  for (int d = 32; d > 0; d >>= 1) v += __shfl_down(v, d);
  if (lane == 0) dout[0] = v;
}

// ---------------- host ----------------
extern "C" void kernel_launch(void* const* d_in, const int* in_sizes, int n_in,
                              void* d_out, int out_size, void* d_ws, size_t ws_size,
                              hipStream_t stream) {
  (void)in_sizes; (void)n_in; (void)out_size; (void)ws_size;
  const int* ids = (const int*)d_in[0];
  const float* hid0 = (const float*)d_in[3];
  const float* cel0 = (const float*)d_in[4];
  const float* emb = (const float*)d_in[5];
  const float* wih = (const float*)d_in[6];
  const float* whh = (const float*)d_in[7];
  const float* bih = (const float*)d_in[8];
  const float* bhh = (const float*)d_in[9];
  const float* wout = (const float*)d_in[10];
  const float* bout = (const float*)d_in[11];
  float* out = (float*)d_out;

  char* ws = (char*)d_ws;
  u16* wbh     = (u16*)(ws + 0ull);            //  65,536,000
  u16* wbl     = (u16*)(ws + 65536000ull);     //  65,536,000
  u16* w3h     = (u16*)(ws + 131072000ull);    //  12,582,912
  u16* w3m     = (u16*)(ws + 143654912ull);    //  12,582,912
  u16* w3l     = (u16*)(ws + 156237824ull);    //  12,582,912
  u16* xs_h    = (u16*)(ws + 168820736ull);    //   4,128,768
  u16* xs_m    = (u16*)(ws + 172949504ull);    //   4,128,768
  u16* xs_l    = (u16*)(ws + 177078272ull);    //   4,128,768
  u16* pp      = (u16*)(ws + 181207040ull);    //     786,432 (6 x 65536 u16)
  u16* hs_hi   = (u16*)(ws + 181993472ull);    //   8,388,608 (4096 rows padded)
  u16* hs_lo   = (u16*)(ws + 190382080ull);    //   8,388,608
  double* cst  = (double*)(ws + 198770688ull); //     524,288
  double* bsum = (double*)(ws + 199294976ull); //      32,768
  u32* part    = (u32*)(ws + 199327744ull);    //  12,096,000
  float* vlab  = (float*)(ws + 211423744ull);  //      16,128
  float* losst = (float*)(ws + 211439872ull);  //         256
  u32* flag    = (u32*)(ws + 211440128ull);    //           4

  const size_t HB = 65536;
  u16* pp0h = pp;            u16* pp0m = pp + HB;     u16* pp0l = pp + 2 * HB;
  u16* pp1h = pp + 3 * HB;   u16* pp1m = pp + 4 * HB; u16* pp1l = pp + 5 * HB;

  k_probe<<<1, 64, 0, stream>>>(flag);
  k_prep_w<<<4096, 256, 0, stream>>>(wout, whh, wih, wbh, wbl, w3h, w3m, w3l);
  k_prep_x<<<2048, 256, 0, stream>>>(ids, emb, hid0, cel0, bih, bhh,
                                     xs_h, xs_m, xs_l, pp0h, pp0m, pp0l,
                                     cst, bsum, hs_hi, hs_lo, losst);
  for (int t = 0; t < NSTEP; t++) {
    const u16* iah = (t & 1) ? pp1h : pp0h;
    const u16* iam = (t & 1) ? pp1m : pp0m;
    const u16* ial = (t & 1) ? pp1l : pp0l;
    u16* oah = (t & 1) ? pp0h : pp1h;
    u16* oam = (t & 1) ? pp0m : pp1m;
    u16* oal = (t & 1) ? pp0l : pp1l;
    k_step<<<256, 256, 0, stream>>>(flag, iah, iam, ial,
        xs_h + (size_t)t * 32768, xs_m + (size_t)t * 32768, xs_l + (size_t)t * 32768,
        w3h, w3m, w3l, bsum, cst,
        hs_hi + (size_t)t * HB, hs_lo + (size_t)t * HB, oah, oam, oal);
  }
  k_logits<<<dim3(32, 250), 256, 0, stream>>>(flag, hs_hi, hs_lo, wbh, wbl, bout, ids, part, vlab);
  k_rowred<<<ROWS, 64, 0, stream>>>(part, vlab, ids, losst, out);
  k_final<<<1, 64, 0, stream>>>(losst, ids, out);
}